// Round 1
// baseline (482.831 us; speedup 1.0000x reference)
//
#include <hip/hip_runtime.h>
#include <stdint.h>

// Problem constants (fixed by reference setup_inputs)
#define D_DIM 4096      // hidden dim (K)
#define E_NUM 64        // experts (N)
#define T_TOK 16384     // tokens (M) = 4*4096
#define TM 16           // tokens per block
#define BK 64           // K-step
#define NSTEP (D_DIM / BK)
#define LDA 72          // LDS row stride in bf16 units (32+... pad -> 2-way-free banks)
#define CAPF 256.0f     // expert_capacity = int(16384/64*1.0)

using bf16x8 = __attribute__((ext_vector_type(8))) short;
using f32x4  = __attribute__((ext_vector_type(4))) float;
typedef unsigned short u16;
typedef unsigned int u32;

__device__ __forceinline__ u32 bf16_rne(u32 u) {
  // round-to-nearest-even fp32 -> bf16 bits (no NaNs in this data)
  return (u + 0x7FFFu + ((u >> 16) & 1u)) >> 16;
}

__device__ __forceinline__ void cvt_split4(const float4 v, u32& h0, u32& h1, u32& l0, u32& l1) {
  float f[4] = {v.x, v.y, v.z, v.w};
  u32 hb[4], lb[4];
#pragma unroll
  for (int i = 0; i < 4; ++i) {
    u32 u = __float_as_uint(f[i]);
    u32 h = bf16_rne(u);
    float fh = __uint_as_float(h << 16);
    float lo = f[i] - fh;            // exact residual
    lb[i] = bf16_rne(__float_as_uint(lo));
    hb[i] = h;
  }
  h0 = hb[0] | (hb[1] << 16); h1 = hb[2] | (hb[3] << 16);
  l0 = lb[0] | (lb[1] << 16); l1 = lb[2] | (lb[3] << 16);
}

// Kernel 0: W (4096x64, [k][e]) -> Wt_hi/Wt_lo bf16 [e][k]; zero S/P accumulators.
__global__ __launch_bounds__(256) void prep_kernel(const float* __restrict__ W,
                                                   u16* __restrict__ Wh, u16* __restrict__ Wl,
                                                   float* __restrict__ S, float* __restrict__ P) {
  int i = blockIdx.x * 256 + threadIdx.x;   // 262144 threads
  int e = i & 63;
  int k = i >> 6;
  float w = W[i];                            // coalesced read of W[k][e]
  u32 u = __float_as_uint(w);
  u32 h = bf16_rne(u);
  float fh = __uint_as_float(h << 16);
  u32 l = bf16_rne(__float_as_uint(w - fh));
  size_t o = (size_t)e * D_DIM + k;          // scattered 2B writes; L2 merges (Wt = 1MB total)
  Wh[o] = (u16)h;
  Wl[o] = (u16)l;
  if (blockIdx.x == 0 && threadIdx.x < 128) {
    if (threadIdx.x < 64) S[threadIdx.x] = 0.f;
    else                  P[threadIdx.x - 64] = 0.f;
  }
}

// Kernel 1: fused router GEMM (split bf16 hi/lo, 3 MFMAs) + softmax + top-1 + S/P accumulation.
// Block: 256 thr = 4 waves. Block tile: 16 tokens x 64 experts. Wave w: experts [16w,16w+16).
__global__ __launch_bounds__(256, 4) void gemm_softmax(
    const float* __restrict__ x, const u16* __restrict__ Wh, const u16* __restrict__ Wl,
    const float* __restrict__ bias, float* __restrict__ out,
    float* __restrict__ S, float* __restrict__ P,
    float* __restrict__ top_p, int* __restrict__ top_i) {
  __shared__ u16 Ah[2][TM * LDA];
  __shared__ u16 Al[2][TM * LDA];
  __shared__ float sm[TM][E_NUM + 1];

  const int tid = threadIdx.x;
  const int lane = tid & 63;
  const int w = tid >> 6;
  const int m = lane & 15;      // A row / B row / C col index
  const int g = lane >> 4;      // k-group
  const int tok_base = blockIdx.x * TM;

  // staging map: thread -> (token ts, 4 consecutive k at kk); 16 thr/token read 64B contiguous
  const int ts = tid >> 4;
  const int kk = (tid & 15) * 4;
  const float* xp = x + (size_t)(tok_base + ts) * D_DIM + kk;

  const int e_loc = w * 16 + m; // this lane's expert for B frags / C col
  const u16* bhp = Wh + (size_t)e_loc * D_DIM + g * 8;
  const u16* blp = Wl + (size_t)e_loc * D_DIM + g * 8;

  f32x4 acc = {0.f, 0.f, 0.f, 0.f};

  // prologue: stage k-step 0
  {
    float4 xv = *(const float4*)xp;
    u32 h0, h1, l0, l1; cvt_split4(xv, h0, h1, l0, l1);
    u32* dh = (u32*)&Ah[0][ts * LDA + kk]; dh[0] = h0; dh[1] = h1;
    u32* dl = (u32*)&Al[0][ts * LDA + kk]; dl[0] = l0; dl[1] = l1;
  }

#pragma unroll 2
  for (int s = 0; s < NSTEP; ++s) {
    const int k0 = s * BK;
    const bool more = (s + 1 < NSTEP);
    float4 xn;
    if (more) xn = *(const float4*)(xp + (s + 1) * BK);   // HBM prefetch for next stage

    // B fragments from L2-resident Wt (16B each)
    bf16x8 bh0 = *(const bf16x8*)(bhp + k0);
    bf16x8 bh1 = *(const bf16x8*)(bhp + k0 + 32);
    bf16x8 bl0 = *(const bf16x8*)(blp + k0);
    bf16x8 bl1 = *(const bf16x8*)(blp + k0 + 32);

    __syncthreads();  // stage s writes visible; stage s-1 reads done
    const int buf = s & 1;
    const u16* abh = &Ah[buf][m * LDA];
    const u16* abl = &Al[buf][m * LDA];
    bf16x8 ah0 = *(const bf16x8*)(abh + g * 8);
    bf16x8 ah1 = *(const bf16x8*)(abh + 32 + g * 8);
    bf16x8 aL0 = *(const bf16x8*)(abl + g * 8);
    bf16x8 aL1 = *(const bf16x8*)(abl + 32 + g * 8);

    acc = __builtin_amdgcn_mfma_f32_16x16x32_bf16(ah0, bh0, acc, 0, 0, 0);
    acc = __builtin_amdgcn_mfma_f32_16x16x32_bf16(aL0, bh0, acc, 0, 0, 0);
    acc = __builtin_amdgcn_mfma_f32_16x16x32_bf16(ah0, bl0, acc, 0, 0, 0);
    acc = __builtin_amdgcn_mfma_f32_16x16x32_bf16(ah1, bh1, acc, 0, 0, 0);
    acc = __builtin_amdgcn_mfma_f32_16x16x32_bf16(aL1, bh1, acc, 0, 0, 0);
    acc = __builtin_amdgcn_mfma_f32_16x16x32_bf16(ah1, bl1, acc, 0, 0, 0);

    if (more) {
      u32 h0, h1, l0, l1; cvt_split4(xn, h0, h1, l0, l1);
      u32* dh = (u32*)&Ah[buf ^ 1][ts * LDA + kk]; dh[0] = h0; dh[1] = h1;
      u32* dl = (u32*)&Al[buf ^ 1][ts * LDA + kk]; dl[0] = l0; dl[1] = l1;
    }
  }

  // ---- epilogue: logits -> LDS (C/D layout: col=lane&15, row=(lane>>4)*4+reg) ----
  const float bb = bias[e_loc];
#pragma unroll
  for (int r = 0; r < 4; ++r) sm[g * 4 + r][e_loc] = acc[r] + bb;
  __syncthreads();

  // softmax: 16 threads per token (aligned within a wave), 4 values each
  const int j = tid >> 4;
  const int c0 = tid & 15;
  float v[4];
#pragma unroll
  for (int i = 0; i < 4; ++i) v[i] = sm[j][c0 + 16 * i];

  float best = v[0]; int bi = c0;
#pragma unroll
  for (int i = 1; i < 4; ++i) {
    if (v[i] > best) { best = v[i]; bi = c0 + 16 * i; }
  }
#pragma unroll
  for (int d = 1; d <= 8; d <<= 1) {     // reduce across the 16-lane token group
    float ob = __shfl_xor(best, d);
    int oi = __shfl_xor(bi, d);
    if (ob > best || (ob == best && oi < bi)) { best = ob; bi = oi; }  // first-max tiebreak
  }
  float ex[4], ssum = 0.f;
#pragma unroll
  for (int i = 0; i < 4; ++i) { ex[i] = __expf(v[i] - best); ssum += ex[i]; }
#pragma unroll
  for (int d = 1; d <= 8; d <<= 1) ssum += __shfl_xor(ssum, d);

  const int gt = tok_base + j;
#pragma unroll
  for (int i = 0; i < 4; ++i) {
    float p = ex[i] / ssum;
    out[(size_t)gt * 64 + c0 + 16 * i] = p;   // probs straight into d_out
    sm[j][c0 + 16 * i] = p;                   // for P reduction (own slots only)
  }
  if (c0 == 0) {
    float tp = 1.0f / ssum;                   // == exp(best-best)/ssum, the top prob
    top_p[gt] = tp;
    top_i[gt] = bi;
    atomicAdd(&S[bi], tp);
  }
  __syncthreads();
  if (tid < 64) {                             // per-expert prob sums over 16 tokens
    float sacc = 0.f;
#pragma unroll
    for (int jj = 0; jj < TM; ++jj) sacc += sm[jj][tid];
    atomicAdd(&P[tid], sacc);
  }
}

// Kernel 2: aux loss scalar
__global__ __launch_bounds__(64) void aux_kernel(float* __restrict__ out,
                                                 const float* __restrict__ S,
                                                 const float* __restrict__ P) {
  int l = threadIdx.x;
  float v = S[l] * P[l];
#pragma unroll
  for (int d = 1; d <= 32; d <<= 1) v += __shfl_xor(v, d);
  if (l == 0) out[(size_t)T_TOK * E_NUM] = 0.01f * 64.0f * v / ((float)T_TOK * (float)T_TOK);
}

// Kernel 3: capacity masking. Fast path: expert prob-sum <= 256 -> all its tokens kept
// (cumsum is monotone, probs > 0). Slow exact path only if an expert overflows.
__global__ __launch_bounds__(256) void finalize_kernel(float* __restrict__ out,
                                                       const float* __restrict__ top_p,
                                                       const int* __restrict__ top_i,
                                                       const float* __restrict__ S) {
  int t = blockIdx.x * 256 + threadIdx.x;     // one thread per token
  int e = top_i[t];
  float se = S[e];
  if (se > CAPF) {
    // exact: inclusive prefix (descending prob order, stable by token index) must be <= 256
    float p = top_p[t];
    float G = 0.f;
    for (int u = 0; u < T_TOK; ++u) {
      if (top_i[u] == e) {
        float q = top_p[u];
        if (q > p || (q == p && u <= t)) G += q;
      }
    }
    if (G > CAPF) {
      float4 z = {0.f, 0.f, 0.f, 0.f};
      float4* row = (float4*)(out + (size_t)t * 64);
#pragma unroll
      for (int i = 0; i < 16; ++i) row[i] = z;
    }
  }
}

extern "C" void kernel_launch(void* const* d_in, const int* in_sizes, int n_in,
                              void* d_out, int out_size, void* d_ws, size_t ws_size,
                              hipStream_t stream) {
  const float* x = (const float*)d_in[0];
  const float* W = (const float*)d_in[1];
  const float* b = (const float*)d_in[2];
  float* out = (float*)d_out;

  // ws layout (~1.19 MB)
  u16* Wh = (u16*)d_ws;
  u16* Wl = Wh + (size_t)E_NUM * D_DIM;
  float* S = (float*)(Wl + (size_t)E_NUM * D_DIM);
  float* P = S + 64;
  float* top_p = P + 64;
  int* top_i = (int*)(top_p + T_TOK);

  prep_kernel<<<(E_NUM * D_DIM) / 256, 256, 0, stream>>>(W, Wh, Wl, S, P);
  gemm_softmax<<<T_TOK / TM, 256, 0, stream>>>(x, Wh, Wl, b, out, S, P, top_p, top_i);
  aux_kernel<<<1, 64, 0, stream>>>(out, S, P);
  finalize_kernel<<<T_TOK / 256, 256, 0, stream>>>(out, top_p, top_i, S);
}